// Round 1
// 435.546 us; speedup vs baseline: 1.0799x; 1.0799x over previous
//
#include <hip/hip_runtime.h>
#include <cstdint>
#include <cstddef>

// VAE forward, fused bf16-MFMA pipeline.
// Sizes fixed: B=32768, INPUT=1024, HIDDEN=1024, LATENT=128.
//
// R5: gemm_bt (128x128, serial stage->drain->compute, MfmaUtil 20.5%)
//     replaced by gemm256: 256x256 tile, 512 thr / 8 waves (2Mx4N), BK=64,
//     8-phase schedule (T3+T4+T5): per K-tile 4 phases x 16 MFMA, one 16KB
//     half-stage per phase, raw s_barrier + counted s_waitcnt vmcnt(6)
//     (never 0 in steady state), setprio(1) around MFMA clusters.
//     Stage region schedule (race-free by construction):
//       P1 -> A2(t+1) into other buffer (that region's reads ended at t-1)
//       P2 -> A1(t+2) into current buffer (A1 read at P1, done)
//       P3 -> B1(t+2) (B1 read at P1)   P4 -> B2(t+2) (B2 read at P2)
//     Boundary vmcnt(6) retires exactly tile t+1's 4 half-stages, leaves
//     t+2's 3 half-stages (6 loads) in flight.
// R4 (kept): gemm2_zkl fused epilogue; BK=64.
// R3 (kept): XCD-pinned 1D grid decode.
// R2 (kept): XOR-swizzled staging (LDS bank conflicts = 0, row stride 128B).

typedef __bf16 bf16x8 __attribute__((ext_vector_type(8)));
typedef float f32x4 __attribute__((ext_vector_type(4)));

__device__ __forceinline__ unsigned short f32_to_bf16(float f) {
  unsigned int u = __float_as_uint(f);
  u += 0x7fffu + ((u >> 16) & 1u);   // round-to-nearest-even (finite values)
  return (unsigned short)(u >> 16);
}

// ---------------- fp32 -> bf16 cast (n divisible by 4) ----------------
__global__ void cast_bf16_k(const float* __restrict__ in,
                            unsigned short* __restrict__ out, int n4) {
  int stride = gridDim.x * blockDim.x;
  for (int i = blockIdx.x * blockDim.x + threadIdx.x; i < n4; i += stride) {
    float4 v = reinterpret_cast<const float4*>(in)[i];
    ushort4 o = make_ushort4(f32_to_bf16(v.x), f32_to_bf16(v.y),
                             f32_to_bf16(v.z), f32_to_bf16(v.w));
    reinterpret_cast<ushort4*>(out)[i] = o;
  }
}

// ------------- fused transpose-convert: 5 jobs, fp32 [K][N] -> bf16 [N][K] -------------
struct TransJob { const float* in; unsigned short* out; int K, N, blkEnd; };

__global__ void transpose_all_k(TransJob j0, TransJob j1, TransJob j2,
                                TransJob j3, TransJob j4) {
  __shared__ float tile[32][33];
  int bid = blockIdx.x;
  TransJob j; int base;
  if (bid < j0.blkEnd)      { j = j0; base = 0; }
  else if (bid < j1.blkEnd) { j = j1; base = j0.blkEnd; }
  else if (bid < j2.blkEnd) { j = j2; base = j1.blkEnd; }
  else if (bid < j3.blkEnd) { j = j3; base = j2.blkEnd; }
  else                      { j = j4; base = j3.blkEnd; }
  int local = bid - base;
  int gxN = j.N >> 5;
  int n0 = (local % gxN) * 32, k0 = (local / gxN) * 32;
  int tx = threadIdx.x, ty = threadIdx.y;  // block is 32x8
#pragma unroll
  for (int r = 0; r < 32; r += 8)
    tile[ty + r][tx] = j.in[(size_t)(k0 + ty + r) * j.N + n0 + tx];
  __syncthreads();
#pragma unroll
  for (int r = 0; r < 32; r += 8)
    j.out[(size_t)(n0 + ty + r) * j.K + k0 + tx] = f32_to_bf16(tile[tx][ty + r]);
}

// async global->LDS, 16B per lane; LDS dest must be contiguous in lane order
__device__ __forceinline__ void gl_lds16(const unsigned short* g, unsigned short* l) {
  __builtin_amdgcn_global_load_lds(
      (__attribute__((address_space(1))) void*)g,
      (__attribute__((address_space(3))) void*)l, 16, 0, 0);
}

// ---------------- GEMM: C = A[M][K] @ BT[N][K]^T + bias ----------------
// 256x256 tile, 512 threads, 8 waves (2Mx4N), BK=64, 8-phase counted-vmcnt
// pipeline. EPI 0: relu->bf16. EPI 2: bernoulli LL rowsum atomicAdd.
// Requires K % 64 == 0 and K >= 128 (NT >= 2), M % 256 == 0, N % 256 == 0.
template <int EPI>
__global__ __launch_bounds__(512, 2) void gemm256(
    const unsigned short* __restrict__ A, const unsigned short* __restrict__ BT,
    int gx, int N, int K,
    const float* __restrict__ bias0,
    unsigned short* __restrict__ outb, float* __restrict__ outf,
    const unsigned short* __restrict__ xbf) {
  __shared__ __align__(16) unsigned short lds[2][2][256 * 64];   // 128 KB

  const int tid = threadIdx.x;
  const int lane = tid & 63;
  const int wave = tid >> 6;
  const int wr = wave >> 2;          // 0..1 (M)
  const int wc = wave & 3;           // 0..3 (N)
  const int lm = lane & 15, lq = lane >> 4;
  const int sw = lm & 7;

  const int bid = blockIdx.x;
  const int xcd = bid & 7;
  const int t8 = bid >> 3;
  const int m0 = (xcd + 8 * (t8 / gx)) * 256;
  const int n0 = (t8 % gx) * 256;
  const int NT = K >> 6;

  // Half-stage regions (16 KB each = 2 chunks/thread):
  //  A1: rows {0-63,128-191}   A2: rows {64-127,192-255}
  //  B1: rows {0-31,64-95,128-159,192-223}   B2: B1+32
  // chunk c = tid + 512*r; LDS slot c&7 of its row holds global chunk
  // (c&7)^(row&7)  (source-swizzled, LDS lane-linear for global_load_lds).
  const unsigned short* gpA[2];
  const unsigned short* gpB[2];
  int loA[2], loB[2];
#pragma unroll
  for (int r = 0; r < 2; ++r) {
    int c = tid + 512 * r, rl = c >> 3, q8 = c & 7;
    int rowA = (rl & 63) + ((rl >> 6) << 7);   // A1 row
    int rowB = (rl & 31) + ((rl >> 5) << 6);   // B1 row
    gpA[r] = A + (size_t)(m0 + rowA) * K + (q8 ^ (rowA & 7)) * 8;
    gpB[r] = BT + (size_t)(n0 + rowB) * K + (q8 ^ (rowB & 7)) * 8;
    loA[r] = rowA * 64 + q8 * 8;
    loB[r] = rowB * 64 + q8 * 8;
  }

  auto stage = [&](int kind, int buf, int kt) {
    // kind: 0=A1, 1=B1, 2=B2, 3=A2  (A2 = A1 rows+64, B2 = B1 rows+32:
    //  row&7 unchanged -> same source chunk swizzle, LDS offset +64*64/+32*64)
#pragma unroll
    for (int r = 0; r < 2; ++r) {
      if (kind == 0)      gl_lds16(gpA[r] + kt * 64,          &lds[buf][0][loA[r]]);
      else if (kind == 3) gl_lds16(gpA[r] + 64 * K + kt * 64, &lds[buf][0][loA[r] + 64 * 64]);
      else if (kind == 1) gl_lds16(gpB[r] + kt * 64,          &lds[buf][1][loB[r]]);
      else                gl_lds16(gpB[r] + 32 * K + kt * 64, &lds[buf][1][loB[r] + 32 * 64]);
    }
  };

  // prologue: tile0 fully + tile1 {A1,B1,B2}; tile1's A2 issues at t0/P1.
  stage(0, 0, 0); stage(1, 0, 0); stage(2, 0, 0); stage(3, 0, 0);
  stage(0, 1, 1); stage(1, 1, 1); stage(2, 1, 1);
  asm volatile("s_waitcnt vmcnt(6)" ::: "memory");   // tile0's 8 loads landed
  __builtin_amdgcn_s_barrier();

  f32x4 acc[8][4] = {};

  const int aRow = (wr * 128 + lm) * 64;
  const int bRow = (wc * 64 + lm) * 64;
  const int c0 = ((0 | lq) ^ sw) * 8;        // k-slice 0 chunk
  const int c1 = ((4 | lq) ^ sw) * 8;        // k-slice 1 chunk

  for (int t = 0; t < NT; ++t) {
    const int b = t & 1;
    const unsigned short* Ab = &lds[b][0][0];
    const unsigned short* Bb = &lds[b][1][0];
    bf16x8 af[4][2], bf1[2][2], bf2[2][2];

    // ---- P1: (m0-3) x (n0-1); 12 ds_read; stage A2(t+1) -> other buf ----
#pragma unroll
    for (int i = 0; i < 4; ++i) {
      af[i][0] = *reinterpret_cast<const bf16x8*>(Ab + aRow + i * 16 * 64 + c0);
      af[i][1] = *reinterpret_cast<const bf16x8*>(Ab + aRow + i * 16 * 64 + c1);
    }
#pragma unroll
    for (int j = 0; j < 2; ++j) {
      bf1[j][0] = *reinterpret_cast<const bf16x8*>(Bb + bRow + j * 16 * 64 + c0);
      bf1[j][1] = *reinterpret_cast<const bf16x8*>(Bb + bRow + j * 16 * 64 + c1);
    }
    if (t + 1 < NT) stage(3, (t + 1) & 1, t + 1);
    __builtin_amdgcn_s_barrier();
    asm volatile("s_waitcnt lgkmcnt(0)" ::: "memory");
    __builtin_amdgcn_s_setprio(1);
#pragma unroll
    for (int s = 0; s < 2; ++s)
#pragma unroll
      for (int i = 0; i < 4; ++i)
#pragma unroll
        for (int j = 0; j < 2; ++j)
          acc[i][j] = __builtin_amdgcn_mfma_f32_16x16x32_bf16(af[i][s], bf1[j][s], acc[i][j], 0, 0, 0);
    __builtin_amdgcn_s_setprio(0);
    __builtin_amdgcn_s_barrier();

    // ---- P2: (m0-3) x (n2-3); 4 ds_read; stage A1(t+2) -> this buf ----
#pragma unroll
    for (int j = 0; j < 2; ++j) {
      bf2[j][0] = *reinterpret_cast<const bf16x8*>(Bb + bRow + (j + 2) * 16 * 64 + c0);
      bf2[j][1] = *reinterpret_cast<const bf16x8*>(Bb + bRow + (j + 2) * 16 * 64 + c1);
    }
    if (t + 2 < NT) stage(0, b, t + 2);
    __builtin_amdgcn_s_barrier();
    asm volatile("s_waitcnt lgkmcnt(0)" ::: "memory");
    __builtin_amdgcn_s_setprio(1);
#pragma unroll
    for (int s = 0; s < 2; ++s)
#pragma unroll
      for (int i = 0; i < 4; ++i)
#pragma unroll
        for (int j = 0; j < 2; ++j)
          acc[i][j + 2] = __builtin_amdgcn_mfma_f32_16x16x32_bf16(af[i][s], bf2[j][s], acc[i][j + 2], 0, 0, 0);
    __builtin_amdgcn_s_setprio(0);
    __builtin_amdgcn_s_barrier();

    // ---- P3: (m4-7) x (n0-1); 8 ds_read (bf1 reused); stage B1(t+2) ----
#pragma unroll
    for (int i = 0; i < 4; ++i) {
      af[i][0] = *reinterpret_cast<const bf16x8*>(Ab + aRow + (64 + i * 16) * 64 + c0);
      af[i][1] = *reinterpret_cast<const bf16x8*>(Ab + aRow + (64 + i * 16) * 64 + c1);
    }
    if (t + 2 < NT) stage(1, b, t + 2);
    __builtin_amdgcn_s_barrier();
    asm volatile("s_waitcnt lgkmcnt(0)" ::: "memory");
    __builtin_amdgcn_s_setprio(1);
#pragma unroll
    for (int s = 0; s < 2; ++s)
#pragma unroll
      for (int i = 0; i < 4; ++i)
#pragma unroll
        for (int j = 0; j < 2; ++j)
          acc[i + 4][j] = __builtin_amdgcn_mfma_f32_16x16x32_bf16(af[i][s], bf1[j][s], acc[i + 4][j], 0, 0, 0);
    __builtin_amdgcn_s_setprio(0);
    __builtin_amdgcn_s_barrier();

    // ---- P4: (m4-7) x (n2-3); 0 ds_read (af,bf2 in regs); stage B2(t+2);
    //      boundary: counted vmcnt retires tile t+1's 4 half-stages ----
    if (t + 2 < NT) stage(2, b, t + 2);
    __builtin_amdgcn_s_barrier();
    __builtin_amdgcn_s_setprio(1);
#pragma unroll
    for (int s = 0; s < 2; ++s)
#pragma unroll
      for (int i = 0; i < 4; ++i)
#pragma unroll
        for (int j = 0; j < 2; ++j)
          acc[i + 4][j + 2] = __builtin_amdgcn_mfma_f32_16x16x32_bf16(af[i][s], bf2[j][s], acc[i + 4][j + 2], 0, 0, 0);
    __builtin_amdgcn_s_setprio(0);
    if (t + 2 < NT)      { asm volatile("s_waitcnt vmcnt(6)" ::: "memory"); }
    else if (t + 1 < NT) { asm volatile("s_waitcnt vmcnt(0)" ::: "memory"); }
    __builtin_amdgcn_s_barrier();
  }

  if (EPI == 0) {
#pragma unroll
    for (int i = 0; i < 8; ++i)
#pragma unroll
      for (int j = 0; j < 4; ++j) {
        int col = n0 + wc * 64 + j * 16 + lm;
        float bias = bias0[col];
#pragma unroll
        for (int r = 0; r < 4; ++r) {
          int row = m0 + wr * 128 + i * 16 + lq * 4 + r;
          float v = acc[i][j][r] + bias;
          outb[(size_t)row * N + col] = f32_to_bf16(fmaxf(v, 0.f));
        }
      }
  } else {
#pragma unroll
    for (int i = 0; i < 8; ++i) {
      float rs[4] = {0.f, 0.f, 0.f, 0.f};
#pragma unroll
      for (int j = 0; j < 4; ++j) {
        int col = n0 + wc * 64 + j * 16 + lm;
        float bias = bias0[col];
#pragma unroll
        for (int r = 0; r < 4; ++r) {
          int row = m0 + wr * 128 + i * 16 + lq * 4 + r;
          float l = acc[i][j][r] + bias;
          unsigned short xb = xbf[(size_t)row * N + col];  // 0x0000 or 0x3F80
          float tt = xb ? -l : l;
          float sp = fmaxf(tt, 0.f) + __logf(1.f + __expf(-fabsf(tt)));
          rs[r] -= sp;
        }
      }
#pragma unroll
      for (int off = 1; off < 16; off <<= 1)
#pragma unroll
        for (int r = 0; r < 4; ++r) rs[r] += __shfl_xor(rs[r], off, 64);
      if (lm == 0) {
#pragma unroll
        for (int r = 0; r < 4; ++r)
          atomicAdd(&outf[m0 + wr * 128 + i * 16 + lq * 4 + r], rs[r]);
      }
    }
  }
}

// -------- GEMM2+zkl fused: S2 = h @ w2t^T (N=256), z/kl in epilogue --------
// 128x256 tile per block, 4 waves each 32 rows x 256 cols; BK=64.
// acc[i][j]: mu at n-tile j (j<8), ls at j+8 -> same lane, no cross-lane.
__global__ __launch_bounds__(256, 1) void gemm2_zkl(
    const unsigned short* __restrict__ A,     // h [B][K]
    const unsigned short* __restrict__ BT,    // w2t [256][K]
    int K,
    const float* __restrict__ bmu, const float* __restrict__ bls,
    const float* __restrict__ eps,            // [B][128]
    unsigned short* __restrict__ z,           // [B][128] bf16
    float* __restrict__ out) {
  __shared__ __align__(16) unsigned short As[128 * 64];   // 16 KB
  __shared__ __align__(16) unsigned short Bs[256 * 64];   // 32 KB

  const int tid = threadIdx.x;
  const int lane = tid & 63;
  const int wave = tid >> 6;
  const int m0 = blockIdx.x * 128;
  const int lm = lane & 15, lq = lane >> 4;

  // A: 1024 chunks (4/thread); B: 2048 chunks (8/thread)
  const unsigned short* agp[4];
  const unsigned short* bgp[8];
#pragma unroll
  for (int r = 0; r < 4; ++r) {
    int c = tid + 256 * r;
    int row = c >> 3, q = (c & 7) ^ (row & 7);
    agp[r] = A + (size_t)(m0 + row) * K + q * 8;
  }
#pragma unroll
  for (int r = 0; r < 8; ++r) {
    int c = tid + 256 * r;
    int row = c >> 3, q = (c & 7) ^ (row & 7);
    bgp[r] = BT + (size_t)row * K + q * 8;
  }
  const int sw = lm & 7;

  f32x4 acc[2][16] = {};

  for (int kt = 0; kt < K; kt += 64) {
#pragma unroll
    for (int r = 0; r < 4; ++r) gl_lds16(agp[r] + kt, As + (tid + 256 * r) * 8);
#pragma unroll
    for (int r = 0; r < 8; ++r) gl_lds16(bgp[r] + kt, Bs + (tid + 256 * r) * 8);
    __syncthreads();

#pragma unroll
    for (int s = 0; s < 2; ++s) {
      const int so = ((s << 2) | lq) ^ sw;
      bf16x8 af[2];
#pragma unroll
      for (int i = 0; i < 2; ++i)
        af[i] = *reinterpret_cast<const bf16x8*>(As + (wave * 32 + i * 16 + lm) * 64 + so * 8);
#pragma unroll
      for (int j = 0; j < 16; ++j) {
        bf16x8 b = *reinterpret_cast<const bf16x8*>(Bs + (j * 16 + lm) * 64 + so * 8);
        acc[0][j] = __builtin_amdgcn_mfma_f32_16x16x32_bf16(af[0], b, acc[0][j], 0, 0, 0);
        acc[1][j] = __builtin_amdgcn_mfma_f32_16x16x32_bf16(af[1], b, acc[1][j], 0, 0, 0);
      }
    }
    __syncthreads();
  }

  // epilogue: z = mu + exp(ls)*eps, kl rowsum
#pragma unroll
  for (int i = 0; i < 2; ++i) {
    float kl[4] = {0.f, 0.f, 0.f, 0.f};
#pragma unroll
    for (int j = 0; j < 8; ++j) {
      int dim = j * 16 + lm;
      float bm = bmu[dim], bl = bls[dim];
#pragma unroll
      for (int r = 0; r < 4; ++r) {
        int row = m0 + wave * 32 + i * 16 + lq * 4 + r;
        float mu = acc[i][j][r] + bm;
        float ls = acc[i][j + 8][r] + bl;
        float e = eps[(size_t)row * 128 + dim];
        z[(size_t)row * 128 + dim] = f32_to_bf16(fmaf(__expf(ls), e, mu));
        kl[r] += 0.5f * (__expf(2.f * ls) + mu * mu - 2.f * ls - 1.f);
      }
    }
#pragma unroll
    for (int off = 1; off < 16; off <<= 1)
#pragma unroll
      for (int r = 0; r < 4; ++r) kl[r] += __shfl_xor(kl[r], off, 64);
    if (lm == 0) {
#pragma unroll
      for (int r = 0; r < 4; ++r)
        out[m0 + wave * 32 + i * 16 + lq * 4 + r] = -kl[r];
    }
  }
}

extern "C" void kernel_launch(void* const* d_in, const int* in_sizes, int n_in,
                              void* d_out, int out_size, void* d_ws, size_t ws_size,
                              hipStream_t stream) {
  const float* x   = (const float*)d_in[0];
  const float* eps = (const float*)d_in[1];
  const float* We1 = (const float*)d_in[2];
  const float* be1 = (const float*)d_in[3];
  const float* Wmu = (const float*)d_in[4];
  const float* bmu = (const float*)d_in[5];
  const float* Wls = (const float*)d_in[6];
  const float* bls = (const float*)d_in[7];
  const float* Wd1 = (const float*)d_in[8];
  const float* bd1 = (const float*)d_in[9];
  const float* Wd2 = (const float*)d_in[10];
  const float* bd2 = (const float*)d_in[11];
  float* out = (float*)d_out;

  const int B = 32768, D = 1024, H = 1024, L = 128;

  char* ws = (char*)d_ws;
  size_t off = 0;
  auto alloc = [&](size_t bytes) {
    void* p = ws + off;
    off += (bytes + 255) & ~(size_t)255;
    return p;
  };
  unsigned short* xbf  = (unsigned short*)alloc((size_t)B * D * 2);   // 64 MB
  unsigned short* w1t  = (unsigned short*)alloc((size_t)H * D * 2);   // 2 MB  [H][D]
  unsigned short* w2t  = (unsigned short*)alloc((size_t)256 * H * 2); // 0.5MB [256][H]
  unsigned short* wd1t = (unsigned short*)alloc((size_t)H * L * 2);   // .25MB [H][L]
  unsigned short* wd2t = (unsigned short*)alloc((size_t)D * H * 2);   // 2 MB  [D][H]
  unsigned short* h    = (unsigned short*)alloc((size_t)B * H * 2);   // 64 MB
  unsigned short* z    = (unsigned short*)alloc((size_t)B * L * 2);   // 8 MB
  unsigned short* hd   = h;  // h is dead after gemm2_zkl -> reuse

  cast_bf16_k<<<2048, 256, 0, stream>>>(x, xbf, B * D / 4);

  TransJob j0{We1, w1t, D, H, 1024};
  TransJob j1{Wmu, w2t, H, L, 1152};
  TransJob j2{Wls, w2t + 128 * H, H, L, 1280};
  TransJob j3{Wd1, wd1t, L, H, 1408};
  TransJob j4{Wd2, wd2t, H, D, 2432};
  transpose_all_k<<<2432, dim3(32, 8), 0, stream>>>(j0, j1, j2, j3, j4);

  // GEMM1: h = relu(x @ We1 + be1)   [M=32768, N=1024, K=1024]
  gemm256<0><<<512, 512, 0, stream>>>(
      xbf, w1t, 4, H, D, be1, h, nullptr, nullptr);
  // GEMM2 + z/kl fused (writes z and out[b] = -kl[b])
  gemm2_zkl<<<B / 128, 256, 0, stream>>>(h, w2t, H, bmu, bls, eps, z, out);
  // GEMM3: hd = relu(z @ Wd1 + bd1)  [M=32768, N=1024, K=128]
  gemm256<0><<<512, 512, 0, stream>>>(
      z, wd1t, 4, H, L, bd1, hd, nullptr, nullptr);
  // GEMM4: bernoulli log-likelihood accumulated into out [K=1024]
  gemm256<2><<<512, 512, 0, stream>>>(
      hd, wd2t, 4, D, H, bd2, nullptr, out, xbf);

  (void)in_sizes; (void)n_in; (void)out_size; (void)ws_size;
}